// Round 3
// baseline (3560.426 us; speedup 1.0000x reference)
//
#include <hip/hip_runtime.h>
#include <math.h>

// RealNVP, 8 layers, B=262144, H=128 — single persistent kernel.
// Per-thread: one sample; x0/x1/sldj/bin kept in REGISTERS across all layers.
// Phases per layer: PREP (fold BN1, sort breakpoints, build level-1 table ST)
// -> HIST (bin search + interval moments + BN2 partial moments) -> PREP2
// (fold BN2, sub-bin crossings U + segment coeffs C) -> STEP (2-round search,
// one float4, 2 fma, coupling update). Grid-wide sync via 2-level device
// barrier (8 group counters + root, agent-scope atomics + __threadfence).

#define BN_ 262144
#define H_ 128
#define NBINS 129
#define NBLK 256
#define NTHR 1024

// ws float offsets
#define OFF_ST   0                 // 4: stats[par] = {sum, sumsq}
#define OFF_BIN  8                 // 256: pm[128], pe[128]
#define OFF_TS   272               // 128: sorted breakpoints
#define OFF_S    400               // float2 ST[129][128]
#define OFF_UP   33424             // float Upiv[129][8]
#define OFF_U    34456             // float U[129][128] (16B aligned)
#define OFF_C    50968             // float4 C[129][132] (16B aligned)
#define OFF_BAR  119080            // 32 barriers * 288 ints

__global__ __launch_bounds__(1024) void k_zero(float* ws) {
    int t = threadIdx.x;
    if (t < 4) ws[OFF_ST + t] = 0.f;
    int* bar = (int*)(ws + OFF_BAR);
    for (int e = t; e < 32 * 288; e += 1024) bar[e] = 0;
}

__device__ __forceinline__ void gbar(int* bar, int idx) {
    __syncthreads();
    if (threadIdx.x == 0) {
        int* base = bar + idx * 288;
        __threadfence();
        if (__hip_atomic_fetch_add(base + (blockIdx.x >> 5) * 32, 1,
                __ATOMIC_ACQ_REL, __HIP_MEMORY_SCOPE_AGENT) == 31) {
            __hip_atomic_fetch_add(base + 256, 1, __ATOMIC_ACQ_REL,
                                   __HIP_MEMORY_SCOPE_AGENT);
        }
        while (__hip_atomic_load(base + 256, __ATOMIC_ACQUIRE,
                                 __HIP_MEMORY_SCOPE_AGENT) < 8)
            __builtin_amdgcn_s_sleep(2);
        __threadfence();
    }
    __syncthreads();
}

__device__ __forceinline__ float bsum(float v, volatile float* tmp, int tid) {
    for (int off = 32; off; off >>= 1) v += __shfl_down(v, off);
    if ((tid & 63) == 0) tmp[tid >> 6] = v;
    __syncthreads();
    float r = 0.f;
    #pragma unroll
    for (int w = 0; w < 16; w++) r += tmp[w];
    __syncthreads();
    return r;
}

__device__ __forceinline__ float4 bsum4(float4 v, volatile float* tmp, int tid) {
    for (int off = 32; off; off >>= 1) {
        v.x += __shfl_down(v.x, off); v.y += __shfl_down(v.y, off);
        v.z += __shfl_down(v.z, off); v.w += __shfl_down(v.w, off);
    }
    if ((tid & 63) == 0) {
        int w = (tid >> 6) * 4;
        tmp[w] = v.x; tmp[w+1] = v.y; tmp[w+2] = v.z; tmp[w+3] = v.w;
    }
    __syncthreads();
    float4 r = make_float4(0.f, 0.f, 0.f, 0.f);
    #pragma unroll
    for (int w = 0; w < 16; w++) {
        r.x += tmp[4*w]; r.y += tmp[4*w+1]; r.z += tmp[4*w+2]; r.w += tmp[4*w+3];
    }
    __syncthreads();
    return r;
}

__global__ __launch_bounds__(1024, 4) void k_flow(
    const float* __restrict__ x,
    const float* __restrict__ v1, const float* __restrict__ g1,
    const float* __restrict__ bn1g, const float* __restrict__ bn1b,
    const float* __restrict__ v2, const float* __restrict__ g2,
    const float* __restrict__ b2,
    const float* __restrict__ bn2g, const float* __restrict__ bn2b,
    const float* __restrict__ wf, const float* __restrict__ bf,
    float* ws, float* __restrict__ out) {

    __shared__ float4 smem4[940];          // 15040 B union for all phases
    float* smem = (float*)smem4;
    int* bar = (int*)(ws + OFF_BAR);
    const int tid = threadIdx.x;
    const int b = blockIdx.x * NTHR + tid;
    int bidx = 0;

    float2 xv = ((const float2*)x)[b];
    float x0v = xv.x, x1v = xv.y, sldj = 0.f;
    int kb = 0;

    { // init: stats of x1 (= layer 0 xin) into stats slot 0
        float* rsc = smem + 1040;
        float s1 = x1v, s2 = x1v * x1v;
        for (int off = 32; off; off >>= 1) {
            s1 += __shfl_down(s1, off); s2 += __shfl_down(s2, off);
        }
        if ((tid & 63) == 0) { rsc[tid >> 6] = s1; rsc[16 + (tid >> 6)] = s2; }
        __syncthreads();
        if (tid == 0) {
            float a = 0.f, c = 0.f;
            for (int w = 0; w < 16; w++) { a += rsc[w]; c += rsc[16 + w]; }
            atomicAdd(&ws[OFF_ST + 0], a);
            atomicAdd(&ws[OFF_ST + 1], c);
        }
    }
    gbar(bar, bidx++);

    #pragma unroll 1
    for (int l = 0; l < 8; l++) {
        const int rev = (l & 1) ? 0 : 1;
        const int par = l & 1;

        // ---------- PREP: blocks 0..127 (unit i); all threads hit barriers ----
        {
            float* sA = smem;        float* sC = smem + 128;
            float* sT = smem + 256;  float* vrow = smem + 384;
            int* order = (int*)(smem + 512);
            float2* scan2 = (float2*)(smem + 640);
            float* red = smem + 896;
            const int i = blockIdx.x, j = tid;
            const bool act = (i < H_) && (j < H_);
            float a = 0.f, c = 0.f, tj = 0.f; int rk = 0;
            if (act) {
                float Ssum = ws[OFF_ST + 2*par], SSq = ws[OFF_ST + 2*par + 1];
                float mx = Ssum * (1.f / BN_);
                float vx = fmaxf(SSq * (1.f / BN_) - mx * mx, 0.f);
                float g1v = g1[l*H_ + j];
                float w1 = (v1[l*H_ + j] >= 0.f) ? g1v : -g1v;
                float r = rsqrtf(vx * g1v * g1v + 1e-5f);
                a = w1 * r * bn1g[l*H_ + j];
                c = bn1b[l*H_ + j] - mx * a;
                tj = (a != 0.f) ? (-c / a) : 3.0e38f;
                sA[j] = a; sC[j] = c; sT[j] = tj;
            }
            __syncthreads();
            if (act) {
                #pragma unroll 8
                for (int q = 0; q < H_; q++) {
                    float tq = sT[q];
                    rk += ((tq < tj) || (tq == tj && q < j)) ? 1 : 0;
                }
                order[rk] = j;
            }
            float vv = act ? v2[l*H_*H_ + i*H_ + j] : 0.f;
            if (act) vrow[j] = vv;
            float n2 = bsum(vv * vv, red, tid);      // its syncs publish order/vrow
            float wsc = act ? (g2[l*H_ + i] / sqrtf(n2)) : 0.f;
            float w = wsc * vv;
            bool bm = act && ((a < 0.f) || (a == 0.f && c > 0.f));
            float base1 = bsum(bm ? w * a : 0.f, red, tid);
            float base0 = bsum(bm ? w * c : 0.f, red, tid);
            if (act) {
                int jj = order[j];
                float aa = sA[jj], cc = sC[jj], vj = vrow[jj];
                float d1 = 0.f, d0 = 0.f;
                if (aa != 0.f) {
                    float sg = (aa > 0.f) ? 1.f : -1.f;
                    float wj = wsc * vj;
                    d1 = sg * wj * aa; d0 = sg * wj * cc;
                }
                scan2[j] = make_float2(d1, d0);
            }
            __syncthreads();
            for (int off = 1; off < H_; off <<= 1) {
                float2 add = make_float2(0.f, 0.f);
                if (act && j >= off) add = scan2[j - off];
                __syncthreads();
                if (act && j >= off) { scan2[j].x += add.x; scan2[j].y += add.y; }
                __syncthreads();
            }
            if (act) {
                float b2i = b2[l*H_ + i];
                float2* ST = (float2*)(ws + OFF_S);
                float2 sj = scan2[j];
                ST[(j + 1)*H_ + i] = make_float2(base1 + sj.x, base0 + sj.y + b2i);
                if (j == 0) ST[i] = make_float2(base1, base0 + b2i);
                if (i == 0) {
                    ws[OFF_TS + rk] = tj;
                    ws[OFF_BIN + j] = 0.f;
                    ws[OFF_BIN + 128 + j] = 0.f;
                    if (j < 2) ws[OFF_ST + 2*(1 - par) + j] = 0.f;
                }
            }
        }
        gbar(bar, bidx++);

        // ---------- HIST: all threads (1 sample each) -------------------------
        {
            float* st = smem;            float* lb = smem + 128;
            float* red1 = smem + 1712;   float* red2 = smem + 2736;
            if (tid < H_) st[tid] = ws[OFF_TS + tid];
            for (int e = tid; e < 4 * 396; e += NTHR) lb[e] = 0.f;
            __syncthreads();
            float xin = rev ? x1v : x0v;
            int pos = 0;
            #pragma unroll
            for (int s = 64; s; s >>= 1) pos += (st[pos + s - 1] < xin) ? s : 0;
            pos += (st[pos] < xin) ? 1 : 0;
            kb = pos;                                 // stays in a register
            float* lbr = lb + ((tid >> 6) & 3) * 396;
            atomicAdd(&lbr[pos], 1.f);
            atomicAdd(&lbr[132 + pos], xin);
            atomicAdd(&lbr[264 + pos], xin * xin);
            __syncthreads();
            const float2* STg = (const float2*)(ws + OFF_S);
            const int i = tid & 127, cch = tid >> 7;
            int k0 = cch * 17, k1 = (k0 + 17 < NBINS) ? k0 + 17 : NBINS;
            float pm = 0.f, pe = 0.f;
            for (int k = k0; k < k1; k++) {
                float cn  = lb[k]       + lb[396 + k]  + lb[792 + k]  + lb[1188 + k];
                float sx  = lb[132 + k] + lb[528 + k]  + lb[924 + k]  + lb[1320 + k];
                float sxx = lb[264 + k] + lb[660 + k]  + lb[1056 + k] + lb[1452 + k];
                float2 s = STg[k*H_ + i];
                pm += s.x * sx + s.y * cn;
                pe += s.x * s.x * sxx + 2.f * s.x * s.y * sx + s.y * s.y * cn;
            }
            red1[tid] = pm; red2[tid] = pe;
            __syncthreads();
            if (tid < H_) {
                float m = 0.f, e2 = 0.f;
                for (int cc = 0; cc < 8; cc++) {
                    m += red1[cc*128 + tid]; e2 += red2[cc*128 + tid];
                }
                atomicAdd(&ws[OFF_BIN + tid], m);
                atomicAdd(&ws[OFF_BIN + 128 + tid], e2);
            }
        }
        gbar(bar, bidx++);

        // ---------- PREP2: blocks 0..128 (bin k) ------------------------------
        {
            float* skey = smem;  float* sval = smem + 128;
            float4* sc4 = (float4*)(smem + 256);
            float* red = smem + 768;
            const int k = blockIdx.x, j = tid;
            const bool act = (k < NBINS) && (j < H_);
            float a = 0.f, c = 0.f, key = INFINITY, w0 = 0.f, w1 = 0.f;
            bool rel = false, actv = false;
            if (act) {
                float mean = ws[OFF_BIN + j] * (1.f / BN_);
                float e2   = ws[OFF_BIN + 128 + j] * (1.f / BN_);
                float var = fmaxf(e2 - mean * mean, 0.f);
                float R = bn2g[l*H_ + j] * rsqrtf(var + 1e-5f);
                float2 mys = ((const float2*)(ws + OFF_S))[k*H_ + j];
                a = mys.x * R;
                c = (mys.y - mean) * R + bn2b[l*H_ + j];
                float lo = (k > 0) ? ws[OFF_TS + k - 1] : -INFINITY;
                float hi = (k < NBINS - 1) ? ws[OFF_TS + k] : INFINITY;
                if (k == 0) actv = (a < 0.f) || (a == 0.f && c > 0.f);
                else        actv = (fmaf(a, lo, c) > 0.f);
                float u = (a != 0.f) ? (-c / a) : INFINITY;
                rel = (a != 0.f) && (u > lo) && (u < hi);
                key = rel ? u : INFINITY;
                skey[j] = key;
                w0 = wf[l*2*H_ + j]; w1 = wf[l*2*H_ + H_ + j];
            }
            __syncthreads();
            int rk = 0;
            if (act) {
                #pragma unroll 8
                for (int q = 0; q < H_; q++) {
                    float kq = skey[q];
                    rk += ((kq < key) || (kq == key && q < j)) ? 1 : 0;
                }
            }
            float4 bbv = make_float4(0.f, 0.f, 0.f, 0.f);
            if (act && actv) bbv = make_float4(w0*a, w0*c, w1*a, w1*c);
            float4 bb = bsum4(bbv, red, tid);
            if (act) {
                float sg = rel ? ((a > 0.f) ? 1.f : -1.f) : 0.f;
                sval[rk] = key;
                sc4[rk] = make_float4(sg*w0*a, sg*w0*c, sg*w1*a, sg*w1*c);
            }
            __syncthreads();
            for (int off = 1; off < H_; off <<= 1) {
                float4 add = make_float4(0.f, 0.f, 0.f, 0.f);
                if (act && j >= off) add = sc4[j - off];
                __syncthreads();
                if (act && j >= off) {
                    sc4[j].x += add.x; sc4[j].y += add.y;
                    sc4[j].z += add.z; sc4[j].w += add.w;
                }
                __syncthreads();
            }
            if (act) {
                float bfx = bf[2*l], bfy = bf[2*l + 1];
                ws[OFF_U + k*H_ + j] = sval[j];
                if (j < 8) ws[OFF_UP + k*8 + j] = sval[16*j + 15];
                float4* Cg = (float4*)(ws + OFF_C) + k * 132;
                float4 sj = sc4[j];
                Cg[j + 1] = make_float4(bb.x + sj.x, bb.y + bfx + sj.y,
                                        bb.z + sj.z, bb.w + bfy + sj.w);
                if (j == 0) Cg[0] = make_float4(bb.x, bb.y + bfx, bb.z, bb.w + bfy);
            }
        }
        gbar(bar, bidx++);

        // ---------- STEP: all threads (1 sample each) -------------------------
        {
            float4* lup4 = (float4*)smem;
            float* lup = smem;
            float* rsc = smem + 1040;
            for (int e = tid; e < NBINS * 8; e += NTHR) lup[e] = ws[OFF_UP + e];
            __syncthreads();
            float xin = rev ? x1v : x0v;
            float xo  = rev ? x0v : x1v;
            float4 p0 = lup4[kb*2], p1 = lup4[kb*2 + 1];
            int s16 = (p0.x<xin)+(p0.y<xin)+(p0.z<xin)+(p0.w<xin)
                    + (p1.x<xin)+(p1.y<xin)+(p1.z<xin)+(p1.w<xin);
            if (s16 > 7) s16 = 7;   // chunk-7 compares then count to 128 exactly
            const float4* Ur = (const float4*)(ws + OFF_U + kb*H_ + s16*16);
            float4 q0 = Ur[0], q1 = Ur[1], q2 = Ur[2], q3 = Ur[3];
            int c2 = (q0.x<xin)+(q0.y<xin)+(q0.z<xin)+(q0.w<xin)
                   + (q1.x<xin)+(q1.y<xin)+(q1.z<xin)+(q1.w<xin)
                   + (q2.x<xin)+(q2.y<xin)+(q2.z<xin)+(q2.w<xin)
                   + (q3.x<xin)+(q3.y<xin)+(q3.z<xin)+(q3.w<xin);
            int s = s16 * 16 + c2;
            float4 C = ((const float4*)(ws + OFF_C))[kb*132 + s];
            float stx = fmaf(C.x, xin, C.y);
            float sty = fmaf(C.z, xin, C.w);
            float sv = tanhf(stx);
            float y = expf(sv) * xo + sty;
            sldj += sv;
            if (l < 7) {
                if (rev) x0v = y; else x1v = y;
                float s1 = y, s2 = y * y;
                for (int off = 32; off; off >>= 1) {
                    s1 += __shfl_down(s1, off); s2 += __shfl_down(s2, off);
                }
                if ((tid & 63) == 0) { rsc[tid >> 6] = s1; rsc[16 + (tid >> 6)] = s2; }
                __syncthreads();
                if (tid == 0) {
                    float aa = 0.f, cc = 0.f;
                    for (int w = 0; w < 16; w++) { aa += rsc[w]; cc += rsc[16 + w]; }
                    atomicAdd(&ws[OFF_ST + 2*(1 - par)], aa);
                    atomicAdd(&ws[OFF_ST + 2*(1 - par) + 1], cc);
                }
            } else {
                float z0 = 1.f / (1.f + expf(-x0v));
                float z1 = 1.f / (1.f + expf(-y));
                ((float2*)out)[b] = make_float2(z0, z1);
                out[2*BN_ + b] = sldj + logf(z0 * (1.f - z0) + 1e-4f)
                                      + logf(z1 * (1.f - z1) + 1e-4f);
            }
        }
        if (l < 7) gbar(bar, bidx++);
    }
}

extern "C" void kernel_launch(void* const* d_in, const int* in_sizes, int n_in,
                              void* d_out, int out_size, void* d_ws, size_t ws_size,
                              hipStream_t stream) {
    const float* x    = (const float*)d_in[0];
    const float* v1   = (const float*)d_in[1];
    const float* g1   = (const float*)d_in[2];
    // d_in[3] = b1: cancels exactly inside BN1 (affine input), unused.
    const float* bn1g = (const float*)d_in[4];
    const float* bn1b = (const float*)d_in[5];
    const float* v2   = (const float*)d_in[6];
    const float* g2   = (const float*)d_in[7];
    const float* b2   = (const float*)d_in[8];
    const float* bn2g = (const float*)d_in[9];
    const float* bn2b = (const float*)d_in[10];
    const float* wf   = (const float*)d_in[11];
    const float* bf   = (const float*)d_in[12];
    float* ws  = (float*)d_ws;
    float* out = (float*)d_out;

    k_zero<<<1, 1024, 0, stream>>>(ws);
    k_flow<<<NBLK, NTHR, 0, stream>>>(x, v1, g1, bn1g, bn1b, v2, g2, b2,
                                      bn2g, bn2b, wf, bf, ws, out);
}

// Round 4
// 1353.961 us; speedup vs baseline: 2.6296x; 2.6296x over previous
//
#include <hip/hip_runtime.h>
#include <math.h>

// RealNVP, 8 layers, B=262144, H=128 — single persistent kernel.
// Per-thread: one sample; x0/x1/sldj/bin kept in REGISTERS across all layers.
// Cross-block coherence WITHOUT L2 flushes: all cross-block table data moves
// via RELAXED agent-scope atomics (sc0/sc1 write-through & bypass loads) so no
// threadfence / wbinv is ever emitted. Grid barrier = relaxed fetch_add tree
// (8 groups of 32 + root) + relaxed spin with s_sleep backoff. __syncthreads()
// drains vmcnt(0) per wave, making prior sc1 stores globally visible before
// the leader's arrive-add.

#define BN_ 262144
#define H_ 128
#define NBINS 129
#define NBLK 256
#define NTHR 1024

// ws float offsets
#define OFF_ST   0                 // 4: stats[par] = {sum, sumsq}
#define OFF_BIN  8                 // 256: pm[128], pe[128]
#define OFF_TS   272               // 128: sorted breakpoints
#define OFF_S    400               // float2 ST[129][128]
#define OFF_UP   33424             // float Upiv[129][8]
#define OFF_U    34456             // float U[129][128] (16B aligned)
#define OFF_C    50968             // float4 C[129][132] (16B aligned)
#define OFF_BAR  119080            // 32 barriers * 288 ints

// ---- coherent (agent-scope, relaxed, no cache maintenance) access helpers ----
__device__ __forceinline__ void cst(float* p, float v) {
    __hip_atomic_store(p, v, __ATOMIC_RELAXED, __HIP_MEMORY_SCOPE_AGENT);
}
__device__ __forceinline__ float cld(const float* p) {
    return __hip_atomic_load((float*)p, __ATOMIC_RELAXED, __HIP_MEMORY_SCOPE_AGENT);
}
__device__ __forceinline__ void cst2(float* p, float2 v) {
    __hip_atomic_store((unsigned long long*)p,
                       __builtin_bit_cast(unsigned long long, v),
                       __ATOMIC_RELAXED, __HIP_MEMORY_SCOPE_AGENT);
}
__device__ __forceinline__ float2 cld2(const float* p) {
    unsigned long long u = __hip_atomic_load((unsigned long long*)p,
                       __ATOMIC_RELAXED, __HIP_MEMORY_SCOPE_AGENT);
    return __builtin_bit_cast(float2, u);
}
__device__ __forceinline__ void cst4(float* p, float4 v) {
    cst2(p, make_float2(v.x, v.y));
    cst2(p + 2, make_float2(v.z, v.w));
}
__device__ __forceinline__ float4 cld4(const float* p) {
    float2 lo = cld2(p), hi = cld2(p + 2);
    return make_float4(lo.x, lo.y, hi.x, hi.y);
}

__global__ __launch_bounds__(1024) void k_zero(float* ws) {
    int t = threadIdx.x;
    if (t < 4) ws[OFF_ST + t] = 0.f;
    int* bar = (int*)(ws + OFF_BAR);
    for (int e = t; e < 32 * 288; e += 1024) bar[e] = 0;
}

__device__ __forceinline__ void gbar(int* bar, int idx) {
    __syncthreads();                       // compiler drains vmcnt(0) per wave
    if (threadIdx.x == 0) {
        int* base = bar + idx * 288;
        asm volatile("s_waitcnt vmcnt(0)" ::: "memory");
        if (__hip_atomic_fetch_add(base + (blockIdx.x >> 5) * 32, 1,
                __ATOMIC_RELAXED, __HIP_MEMORY_SCOPE_AGENT) == 31) {
            __hip_atomic_fetch_add(base + 256, 1, __ATOMIC_RELAXED,
                                   __HIP_MEMORY_SCOPE_AGENT);
        }
        while (__hip_atomic_load(base + 256, __ATOMIC_RELAXED,
                                 __HIP_MEMORY_SCOPE_AGENT) < 8)
            __builtin_amdgcn_s_sleep(8);
    }
    __syncthreads();
}

__device__ __forceinline__ float bsum(float v, volatile float* tmp, int tid) {
    for (int off = 32; off; off >>= 1) v += __shfl_down(v, off);
    if ((tid & 63) == 0) tmp[tid >> 6] = v;
    __syncthreads();
    float r = 0.f;
    #pragma unroll
    for (int w = 0; w < 16; w++) r += tmp[w];
    __syncthreads();
    return r;
}

__device__ __forceinline__ float4 bsum4(float4 v, volatile float* tmp, int tid) {
    for (int off = 32; off; off >>= 1) {
        v.x += __shfl_down(v.x, off); v.y += __shfl_down(v.y, off);
        v.z += __shfl_down(v.z, off); v.w += __shfl_down(v.w, off);
    }
    if ((tid & 63) == 0) {
        int w = (tid >> 6) * 4;
        tmp[w] = v.x; tmp[w+1] = v.y; tmp[w+2] = v.z; tmp[w+3] = v.w;
    }
    __syncthreads();
    float4 r = make_float4(0.f, 0.f, 0.f, 0.f);
    #pragma unroll
    for (int w = 0; w < 16; w++) {
        r.x += tmp[4*w]; r.y += tmp[4*w+1]; r.z += tmp[4*w+2]; r.w += tmp[4*w+3];
    }
    __syncthreads();
    return r;
}

__global__ __launch_bounds__(1024, 4) void k_flow(
    const float* __restrict__ x,
    const float* __restrict__ v1, const float* __restrict__ g1,
    const float* __restrict__ bn1g, const float* __restrict__ bn1b,
    const float* __restrict__ v2, const float* __restrict__ g2,
    const float* __restrict__ b2,
    const float* __restrict__ bn2g, const float* __restrict__ bn2b,
    const float* __restrict__ wf, const float* __restrict__ bf,
    float* ws, float* __restrict__ out) {

    __shared__ float4 smem4[940];          // 15040 B union for all phases
    float* smem = (float*)smem4;
    int* bar = (int*)(ws + OFF_BAR);
    const int tid = threadIdx.x;
    const int b = blockIdx.x * NTHR + tid;
    int bidx = 0;

    float2 xv = ((const float2*)x)[b];
    float x0v = xv.x, x1v = xv.y, sldj = 0.f;
    int kb = 0;

    { // init: stats of x1 (= layer 0 xin) into stats slot 0
        float* rsc = smem + 1040;
        float s1 = x1v, s2 = x1v * x1v;
        for (int off = 32; off; off >>= 1) {
            s1 += __shfl_down(s1, off); s2 += __shfl_down(s2, off);
        }
        if ((tid & 63) == 0) { rsc[tid >> 6] = s1; rsc[16 + (tid >> 6)] = s2; }
        __syncthreads();
        if (tid == 0) {
            float a = 0.f, c = 0.f;
            for (int w = 0; w < 16; w++) { a += rsc[w]; c += rsc[16 + w]; }
            atomicAdd(&ws[OFF_ST + 0], a);
            atomicAdd(&ws[OFF_ST + 1], c);
        }
    }
    gbar(bar, bidx++);

    #pragma unroll 1
    for (int l = 0; l < 8; l++) {
        const int rev = (l & 1) ? 0 : 1;
        const int par = l & 1;

        // ---------- PREP: blocks 0..127 (unit i); all threads hit barriers ----
        {
            float* sA = smem;        float* sC = smem + 128;
            float* sT = smem + 256;  float* vrow = smem + 384;
            int* order = (int*)(smem + 512);
            float2* scan2 = (float2*)(smem + 640);
            float* red = smem + 896;
            const int i = blockIdx.x, j = tid;
            const bool act = (i < H_) && (j < H_);
            float a = 0.f, c = 0.f, tj = 0.f; int rk = 0;
            if (act) {
                float Ssum = cld(ws + OFF_ST + 2*par);
                float SSq  = cld(ws + OFF_ST + 2*par + 1);
                float mx = Ssum * (1.f / BN_);
                float vx = fmaxf(SSq * (1.f / BN_) - mx * mx, 0.f);
                float g1v = g1[l*H_ + j];
                float w1 = (v1[l*H_ + j] >= 0.f) ? g1v : -g1v;
                float r = rsqrtf(vx * g1v * g1v + 1e-5f);
                a = w1 * r * bn1g[l*H_ + j];
                c = bn1b[l*H_ + j] - mx * a;
                tj = (a != 0.f) ? (-c / a) : 3.0e38f;
                sA[j] = a; sC[j] = c; sT[j] = tj;
            }
            __syncthreads();
            if (act) {
                #pragma unroll 8
                for (int q = 0; q < H_; q++) {
                    float tq = sT[q];
                    rk += ((tq < tj) || (tq == tj && q < j)) ? 1 : 0;
                }
                order[rk] = j;
            }
            float vv = act ? v2[l*H_*H_ + i*H_ + j] : 0.f;
            if (act) vrow[j] = vv;
            float n2 = bsum(vv * vv, red, tid);      // its syncs publish order/vrow
            float wsc = act ? (g2[l*H_ + i] / sqrtf(n2)) : 0.f;
            float w = wsc * vv;
            bool bm = act && ((a < 0.f) || (a == 0.f && c > 0.f));
            float base1 = bsum(bm ? w * a : 0.f, red, tid);
            float base0 = bsum(bm ? w * c : 0.f, red, tid);
            if (act) {
                int jj = order[j];
                float aa = sA[jj], cc = sC[jj], vj = vrow[jj];
                float d1 = 0.f, d0 = 0.f;
                if (aa != 0.f) {
                    float sg = (aa > 0.f) ? 1.f : -1.f;
                    float wj = wsc * vj;
                    d1 = sg * wj * aa; d0 = sg * wj * cc;
                }
                scan2[j] = make_float2(d1, d0);
            }
            __syncthreads();
            for (int off = 1; off < H_; off <<= 1) {
                float2 add = make_float2(0.f, 0.f);
                if (act && j >= off) add = scan2[j - off];
                __syncthreads();
                if (act && j >= off) { scan2[j].x += add.x; scan2[j].y += add.y; }
                __syncthreads();
            }
            if (act) {
                float b2i = b2[l*H_ + i];
                float* ST = ws + OFF_S;
                float2 sj = scan2[j];
                cst2(ST + 2*((j + 1)*H_ + i),
                     make_float2(base1 + sj.x, base0 + sj.y + b2i));
                if (j == 0) cst2(ST + 2*i, make_float2(base1, base0 + b2i));
                if (i == 0) {
                    cst(ws + OFF_TS + rk, tj);
                    cst(ws + OFF_BIN + j, 0.f);
                    cst(ws + OFF_BIN + 128 + j, 0.f);
                    if (j < 2) cst(ws + OFF_ST + 2*(1 - par) + j, 0.f);
                }
            }
        }
        gbar(bar, bidx++);

        // ---------- HIST: all threads (1 sample each) -------------------------
        {
            float* st = smem;            float* lb = smem + 128;
            float* red1 = smem + 1712;   float* red2 = smem + 2736;
            if (tid < H_) st[tid] = cld(ws + OFF_TS + tid);
            for (int e = tid; e < 4 * 396; e += NTHR) lb[e] = 0.f;
            __syncthreads();
            float xin = rev ? x1v : x0v;
            int pos = 0;
            #pragma unroll
            for (int s = 64; s; s >>= 1) pos += (st[pos + s - 1] < xin) ? s : 0;
            pos += (st[pos] < xin) ? 1 : 0;
            kb = pos;                                 // stays in a register
            float* lbr = lb + ((tid >> 6) & 3) * 396;
            atomicAdd(&lbr[pos], 1.f);
            atomicAdd(&lbr[132 + pos], xin);
            atomicAdd(&lbr[264 + pos], xin * xin);
            __syncthreads();
            const float* STg = ws + OFF_S;
            const int i = tid & 127, cch = tid >> 7;
            int k0 = cch * 17, k1 = (k0 + 17 < NBINS) ? k0 + 17 : NBINS;
            float pm = 0.f, pe = 0.f;
            #pragma unroll 4
            for (int k = k0; k < k1; k++) {
                float cn  = lb[k]       + lb[396 + k]  + lb[792 + k]  + lb[1188 + k];
                float sx  = lb[132 + k] + lb[528 + k]  + lb[924 + k]  + lb[1320 + k];
                float sxx = lb[264 + k] + lb[660 + k]  + lb[1056 + k] + lb[1452 + k];
                float2 s = cld2(STg + 2*(k*H_ + i));
                pm += s.x * sx + s.y * cn;
                pe += s.x * s.x * sxx + 2.f * s.x * s.y * sx + s.y * s.y * cn;
            }
            red1[tid] = pm; red2[tid] = pe;
            __syncthreads();
            if (tid < H_) {
                float m = 0.f, e2 = 0.f;
                for (int cc = 0; cc < 8; cc++) {
                    m += red1[cc*128 + tid]; e2 += red2[cc*128 + tid];
                }
                atomicAdd(&ws[OFF_BIN + tid], m);
                atomicAdd(&ws[OFF_BIN + 128 + tid], e2);
            }
        }
        gbar(bar, bidx++);

        // ---------- PREP2: blocks 0..128 (bin k) ------------------------------
        {
            float* skey = smem;  float* sval = smem + 128;
            float4* sc4 = (float4*)(smem + 256);
            float* red = smem + 768;
            const int k = blockIdx.x, j = tid;
            const bool act = (k < NBINS) && (j < H_);
            float a = 0.f, c = 0.f, key = INFINITY, w0 = 0.f, w1 = 0.f;
            bool rel = false, actv = false;
            if (act) {
                float mean = cld(ws + OFF_BIN + j) * (1.f / BN_);
                float e2   = cld(ws + OFF_BIN + 128 + j) * (1.f / BN_);
                float var = fmaxf(e2 - mean * mean, 0.f);
                float R = bn2g[l*H_ + j] * rsqrtf(var + 1e-5f);
                float2 mys = cld2(ws + OFF_S + 2*(k*H_ + j));
                a = mys.x * R;
                c = (mys.y - mean) * R + bn2b[l*H_ + j];
                float lo = (k > 0) ? cld(ws + OFF_TS + k - 1) : -INFINITY;
                float hi = (k < NBINS - 1) ? cld(ws + OFF_TS + k) : INFINITY;
                if (k == 0) actv = (a < 0.f) || (a == 0.f && c > 0.f);
                else        actv = (fmaf(a, lo, c) > 0.f);
                float u = (a != 0.f) ? (-c / a) : INFINITY;
                rel = (a != 0.f) && (u > lo) && (u < hi);
                key = rel ? u : INFINITY;
                skey[j] = key;
                w0 = wf[l*2*H_ + j]; w1 = wf[l*2*H_ + H_ + j];
            }
            __syncthreads();
            int rk = 0;
            if (act) {
                #pragma unroll 8
                for (int q = 0; q < H_; q++) {
                    float kq = skey[q];
                    rk += ((kq < key) || (kq == key && q < j)) ? 1 : 0;
                }
            }
            float4 bbv = make_float4(0.f, 0.f, 0.f, 0.f);
            if (act && actv) bbv = make_float4(w0*a, w0*c, w1*a, w1*c);
            float4 bb = bsum4(bbv, red, tid);
            if (act) {
                float sg = rel ? ((a > 0.f) ? 1.f : -1.f) : 0.f;
                sval[rk] = key;
                sc4[rk] = make_float4(sg*w0*a, sg*w0*c, sg*w1*a, sg*w1*c);
            }
            __syncthreads();
            for (int off = 1; off < H_; off <<= 1) {
                float4 add = make_float4(0.f, 0.f, 0.f, 0.f);
                if (act && j >= off) add = sc4[j - off];
                __syncthreads();
                if (act && j >= off) {
                    sc4[j].x += add.x; sc4[j].y += add.y;
                    sc4[j].z += add.z; sc4[j].w += add.w;
                }
                __syncthreads();
            }
            if (act) {
                float bfx = bf[2*l], bfy = bf[2*l + 1];
                cst(ws + OFF_U + k*H_ + j, sval[j]);
                if (j < 8) cst(ws + OFF_UP + k*8 + j, sval[16*j + 15]);
                float* Cg = ws + OFF_C + 4 * (k * 132);
                float4 sj = sc4[j];
                cst4(Cg + 4*(j + 1),
                     make_float4(bb.x + sj.x, bb.y + bfx + sj.y,
                                 bb.z + sj.z, bb.w + bfy + sj.w));
                if (j == 0)
                    cst4(Cg, make_float4(bb.x, bb.y + bfx, bb.z, bb.w + bfy));
            }
        }
        gbar(bar, bidx++);

        // ---------- STEP: all threads (1 sample each) -------------------------
        {
            float4* lup4 = (float4*)smem;
            float* lup = smem;
            float* rsc = smem + 1040;
            for (int e = tid; e < NBINS * 8; e += NTHR) lup[e] = cld(ws + OFF_UP + e);
            __syncthreads();
            float xin = rev ? x1v : x0v;
            float xo  = rev ? x0v : x1v;
            float4 p0 = lup4[kb*2], p1 = lup4[kb*2 + 1];
            int s16 = (p0.x<xin)+(p0.y<xin)+(p0.z<xin)+(p0.w<xin)
                    + (p1.x<xin)+(p1.y<xin)+(p1.z<xin)+(p1.w<xin);
            if (s16 > 7) s16 = 7;   // chunk-7 compares then count to 128 exactly
            const float* Ub = ws + OFF_U + kb*H_ + s16*16;
            float4 q0 = cld4(Ub), q1 = cld4(Ub + 4), q2 = cld4(Ub + 8), q3 = cld4(Ub + 12);
            int c2 = (q0.x<xin)+(q0.y<xin)+(q0.z<xin)+(q0.w<xin)
                   + (q1.x<xin)+(q1.y<xin)+(q1.z<xin)+(q1.w<xin)
                   + (q2.x<xin)+(q2.y<xin)+(q2.z<xin)+(q2.w<xin)
                   + (q3.x<xin)+(q3.y<xin)+(q3.z<xin)+(q3.w<xin);
            int s = s16 * 16 + c2;
            float4 C = cld4(ws + OFF_C + 4*(kb*132 + s));
            float stx = fmaf(C.x, xin, C.y);
            float sty = fmaf(C.z, xin, C.w);
            float sv = tanhf(stx);
            float y = expf(sv) * xo + sty;
            sldj += sv;
            if (l < 7) {
                if (rev) x0v = y; else x1v = y;
                float s1 = y, s2 = y * y;
                for (int off = 32; off; off >>= 1) {
                    s1 += __shfl_down(s1, off); s2 += __shfl_down(s2, off);
                }
                if ((tid & 63) == 0) { rsc[tid >> 6] = s1; rsc[16 + (tid >> 6)] = s2; }
                __syncthreads();
                if (tid == 0) {
                    float aa = 0.f, cc = 0.f;
                    for (int w = 0; w < 16; w++) { aa += rsc[w]; cc += rsc[16 + w]; }
                    atomicAdd(&ws[OFF_ST + 2*(1 - par)], aa);
                    atomicAdd(&ws[OFF_ST + 2*(1 - par) + 1], cc);
                }
            } else {
                float z0 = 1.f / (1.f + expf(-x0v));
                float z1 = 1.f / (1.f + expf(-y));
                ((float2*)out)[b] = make_float2(z0, z1);
                out[2*BN_ + b] = sldj + logf(z0 * (1.f - z0) + 1e-4f)
                                      + logf(z1 * (1.f - z1) + 1e-4f);
            }
        }
        if (l < 7) gbar(bar, bidx++);
    }
}

extern "C" void kernel_launch(void* const* d_in, const int* in_sizes, int n_in,
                              void* d_out, int out_size, void* d_ws, size_t ws_size,
                              hipStream_t stream) {
    const float* x    = (const float*)d_in[0];
    const float* v1   = (const float*)d_in[1];
    const float* g1   = (const float*)d_in[2];
    // d_in[3] = b1: cancels exactly inside BN1 (affine input), unused.
    const float* bn1g = (const float*)d_in[4];
    const float* bn1b = (const float*)d_in[5];
    const float* v2   = (const float*)d_in[6];
    const float* g2   = (const float*)d_in[7];
    const float* b2   = (const float*)d_in[8];
    const float* bn2g = (const float*)d_in[9];
    const float* bn2b = (const float*)d_in[10];
    const float* wf   = (const float*)d_in[11];
    const float* bf   = (const float*)d_in[12];
    float* ws  = (float*)d_ws;
    float* out = (float*)d_out;

    k_zero<<<1, 1024, 0, stream>>>(ws);
    k_flow<<<NBLK, NTHR, 0, stream>>>(x, v1, g1, bn1g, bn1b, v2, g2, b2,
                                      bn2g, bn2b, wf, bf, ws, out);
}

// Round 5
// 448.092 us; speedup vs baseline: 7.9457x; 3.0216x over previous
//
#include <hip/hip_runtime.h>
#include <math.h>

// RealNVP, 8 layers, B=262144, H=128. Multi-kernel (grid sync proven unviable
// on gfx950: fences => L2-flush storms, bypass atomics => uncacheable tables).
// Per layer: k_bin (BN1 fold + rank + binning + interval moments + BN2 moment
// fold, block 0 writes ST/ts) -> k_prep2 (per-bin segment tables U/UP/C)
// -> k_step (2-round search + 1 float4 + 2 fma + coupling, fused next-layer
// stats). v2 pre-transposed once (v2T) for coalesced toggle walks; weight-norm
// scales wsc precomputed once.

#define BN_ 262144
#define H_ 128
#define NBINS 129

// ws float offsets
#define OFF_STAT 0                       // 16: stats[l] = {sum,sumsq}, l=0..7
#define OFF_PM   16                      // 8*256: pm[128],pe[128] per layer
#define OFF_TS   2064                    // 128: sorted breakpoints (cur layer)
#define OFF_X0   4096                    // x0[BN]
#define OFF_X1   (OFF_X0 + BN_)         // x1[BN]
#define OFF_SL   (OFF_X0 + 2*BN_)       // sldj[BN]
#define OFF_KB   (OFF_X0 + 3*BN_)       // uchar[BN]
#define OFF_V2T  (OFF_KB + BN_/4)       // 8*128*128: v2T[l][j][i]
#define OFF_WSC  (OFF_V2T + 8*H_*H_)    // 8*128: g2/||v2row||
#define OFF_S    (OFF_WSC + 8*H_)       // float2 ST[129][128]
#define OFF_UP   (OFF_S + NBINS*H_*2)   // float Upiv[129][8]
#define OFF_U    (OFF_UP + NBINS*8)     // float U[129][128]
#define OFF_C    (OFF_U + NBINS*H_)     // float4 C[129][132]

__device__ __forceinline__ float4 bsum4(float4 v, volatile float* tmp, int tid) {
    for (int off = 32; off; off >>= 1) {
        v.x += __shfl_down(v.x, off); v.y += __shfl_down(v.y, off);
        v.z += __shfl_down(v.z, off); v.w += __shfl_down(v.w, off);
    }
    if ((tid & 63) == 0) {
        int w = (tid >> 6) * 4;
        tmp[w] = v.x; tmp[w+1] = v.y; tmp[w+2] = v.z; tmp[w+3] = v.w;
    }
    __syncthreads();
    float4 r = make_float4(tmp[0]+tmp[4], tmp[1]+tmp[5],
                           tmp[2]+tmp[6], tmp[3]+tmp[7]);
    __syncthreads();
    return r;
}

// 256x1024: stats of x1 (layer-0 xin) + v2 transpose + wsc precompute.
__global__ __launch_bounds__(1024) void k_init(const float* __restrict__ x,
    const float* __restrict__ v2, const float* __restrict__ g2,
    float* __restrict__ ws) {
    const int tid = threadIdx.x;
    __shared__ float rs[16], rss[16], w2[16];
    int b = blockIdx.x * 1024 + tid;
    float2 xv = ((const float2*)x)[b];
    float s1 = xv.y, s2 = xv.y * xv.y;
    for (int off = 32; off; off >>= 1) {
        s1 += __shfl_down(s1, off); s2 += __shfl_down(s2, off);
    }
    if ((tid & 63) == 0) { rs[tid>>6] = s1; rss[tid>>6] = s2; }
    __syncthreads();
    if (tid == 0) {
        float a = 0.f, c = 0.f;
        for (int w = 0; w < 16; w++) { a += rs[w]; c += rss[w]; }
        atomicAdd(&ws[OFF_STAT + 0], a);
        atomicAdd(&ws[OFF_STAT + 1], c);
    }
    if (blockIdx.x < 128) {
        const int l = blockIdx.x >> 4, i0 = (blockIdx.x & 15) * 8;
        const int iloc = tid >> 7, j = tid & 127;
        float val = v2[(l*H_ + i0 + iloc)*H_ + j];
        ws[OFF_V2T + (l*H_ + j)*H_ + i0 + iloc] = val;
        float s = val * val;
        for (int off = 32; off; off >>= 1) s += __shfl_down(s, off);
        if ((tid & 63) == 0) w2[tid >> 6] = s;
        __syncthreads();
        if (tid < 8)
            ws[OFF_WSC + l*H_ + i0 + tid] =
                g2[l*H_ + i0 + tid] / sqrtf(w2[2*tid] + w2[2*tid+1]);
    }
}

// 256x1024: BN1 fold + rank-sort + per-sample binning + LDS interval moments
// + BN2 moment fold (prefix walk over toggles, v2T coalesced). Block 0 also
// writes ST table + sorted breakpoints.
__global__ __launch_bounds__(1024) void k_bin(
    const float* __restrict__ x,
    const float* __restrict__ v1, const float* __restrict__ g1,
    const float* __restrict__ bn1g, const float* __restrict__ bn1b,
    const float* __restrict__ b2,
    float* __restrict__ ws, int l, int rev) {
    __shared__ float sA[H_], sC[H_], sTun[H_], sTs[H_], wscs[H_], b2s[H_];
    __shared__ int ordr[H_];
    __shared__ float pT1[8][H_], pT0[8][H_], pB1[8][H_], pB0[8][H_];
    __shared__ float scratch[4656];   // [0,1024) prank | [1024,2608) lb | [2608,4656) red
    const int tid = threadIdx.x;
    const float* v2T = ws + OFF_V2T + l*H_*H_;

    if (tid < H_) {                   // phase 0: BN1 fold (block-redundant)
        float Ssum = ws[OFF_STAT + 2*l], SSq = ws[OFF_STAT + 2*l + 1];
        float mx = Ssum * (1.f / BN_);
        float vx = fmaxf(SSq * (1.f / BN_) - mx * mx, 0.f);
        float g1v = g1[l*H_ + tid];
        float w1 = (v1[l*H_ + tid] >= 0.f) ? g1v : -g1v;
        float r = rsqrtf(vx * g1v * g1v + 1e-5f);
        float a = w1 * r * bn1g[l*H_ + tid];
        float c = bn1b[l*H_ + tid] - mx * a;
        sA[tid] = a; sC[tid] = c;
        sTun[tid] = (a != 0.f) ? (-c / a) : 3.0e38f;
        wscs[tid] = ws[OFF_WSC + l*H_ + tid];
        b2s[tid] = b2[l*H_ + tid];
    }
    __syncthreads();
    {                                 // phase 1: rank (8 partial segs)
        int* prank = (int*)scratch;
        int j = tid & 127, seg = tid >> 7;
        float tj = sTun[j];
        int pr = 0;
        #pragma unroll
        for (int m = 0; m < 16; ++m) {
            int q = seg*16 + m;
            float tq = sTun[q];
            pr += (tq < tj || (tq == tj && q < j)) ? 1 : 0;
        }
        prank[seg*128 + j] = pr;
        __syncthreads();
        if (tid < H_) {
            int rk = 0;
            #pragma unroll
            for (int s = 0; s < 8; ++s) rk += prank[s*128 + tid];
            ordr[rk] = tid;
            float tv = sTun[tid];
            sTs[rk] = tv;
            if (blockIdx.x == 0) ws[OFF_TS + rk] = tv;
        }
    }
    __syncthreads();
    {                                 // phase 2: toggle/base partials; zero lb
        int i = tid & 127, cc = tid >> 7;
        float b1 = 0.f, b0 = 0.f, d1 = 0.f, d0 = 0.f;
        #pragma unroll 4
        for (int m = 0; m < 16; ++m) {
            int j2 = cc*16 + m;
            float vj = v2T[j2*H_ + i];
            float aj = sA[j2], cj = sC[j2];
            if ((aj < 0.f) || (aj == 0.f && cj > 0.f)) { b1 += vj*aj; b0 += vj*cj; }
            int jm = ordr[j2];
            float am = sA[jm];
            if (am != 0.f) {
                float vm = v2T[jm*H_ + i];
                float sg = (am > 0.f) ? 1.f : -1.f;
                d1 += sg*vm*am; d0 += sg*vm*sC[jm];
            }
        }
        pT1[cc][i] = d1; pT0[cc][i] = d0; pB1[cc][i] = b1; pB0[cc][i] = b0;
        float* lb = scratch + 1024;
        for (int e = tid; e < 1584; e += 1024) lb[e] = 0.f;
    }
    __syncthreads();
    const int b = blockIdx.x * 1024 + tid;
    {                                 // phase 3: bin + LDS hist
        float xin = (l == 0) ? ((const float2*)x)[b].y
                             : ws[OFF_X0 + (rev ? BN_ : 0) + b];
        int pos = 0;
        #pragma unroll
        for (int s = 64; s; s >>= 1) pos += (sTs[pos + s - 1] < xin) ? s : 0;
        pos += (sTs[pos] < xin) ? 1 : 0;
        ((unsigned char*)(ws + OFF_KB))[b] = (unsigned char)pos;
        float* lbr = scratch + 1024 + ((tid >> 6) & 3) * 396;
        atomicAdd(&lbr[pos], 1.f);
        atomicAdd(&lbr[132 + pos], xin);
        atomicAdd(&lbr[264 + pos], xin * xin);
    }
    __syncthreads();
    {                                 // phase 4: moment fold + ST write (blk 0)
        const float* lb = scratch + 1024;
        int i = tid & 127, cc = tid >> 7;
        float S1 = 0.f, S0 = 0.f;
        #pragma unroll
        for (int c2 = 0; c2 < 8; ++c2) {
            S1 += pB1[c2][i]; S0 += pB0[c2][i];
            if (c2 < cc) { S1 += pT1[c2][i]; S0 += pT0[c2][i]; }
        }
        float wsci = wscs[i], b2i = b2s[i];
        float pm = 0.f, pe = 0.f;
        int kend = (cc == 7) ? 17 : 16;
        int k = 16 * cc;
        float2* STg = (float2*)(ws + OFF_S);
        for (int r = 0; r < kend; ++r, ++k) {
            float cn  = lb[k] + lb[396+k] + lb[792+k] + lb[1188+k];
            float sx  = lb[132+k] + lb[528+k] + lb[924+k] + lb[1320+k];
            float sxx = lb[264+k] + lb[660+k] + lb[1056+k] + lb[1452+k];
            float A = wsci * S1;
            float B = fmaf(wsci, S0, b2i);
            if (blockIdx.x == 0) STg[k*H_ + i] = make_float2(A, B);
            pm += A*sx + B*cn;
            pe += A*A*sxx + 2.f*A*B*sx + B*B*cn;
            if (k < 128) {
                int jm = ordr[k];
                float am = sA[jm];
                if (am != 0.f) {
                    float vm = v2T[jm*H_ + i];
                    float sg = (am > 0.f) ? 1.f : -1.f;
                    S1 += sg*vm*am; S0 += sg*vm*sC[jm];
                }
            }
        }
        float* red1 = scratch + 2608;
        float* red2 = scratch + 3632;
        red1[tid] = pm; red2[tid] = pe;
        __syncthreads();
        if (tid < H_) {
            float m = 0.f, e2 = 0.f;
            #pragma unroll
            for (int c2 = 0; c2 < 8; ++c2) {
                m += red1[c2*128 + tid]; e2 += red2[c2*128 + tid];
            }
            atomicAdd(&ws[OFF_PM + 256*l + tid], m);
            atomicAdd(&ws[OFF_PM + 256*l + 128 + tid], e2);
        }
    }
}

// 129x128: block k = bin k. BN2 fold (2 loads of pm/pe), in-bin crossings,
// rank, wf-weighted toggle scan -> U/UP/C segment tables.
__global__ __launch_bounds__(128) void k_prep2(
    const float* __restrict__ bn2g, const float* __restrict__ bn2b,
    const float* __restrict__ wf, const float* __restrict__ bf,
    float* __restrict__ ws, int l) {
    const int j = threadIdx.x, k = blockIdx.x;
    __shared__ float skey[H_], sval[H_];
    __shared__ float4 sc4[H_];
    __shared__ float red[8];
    float pmv = ws[OFF_PM + 256*l + j], pev = ws[OFF_PM + 256*l + 128 + j];
    float mean = pmv * (1.f / BN_);
    float var = fmaxf(pev * (1.f / BN_) - mean * mean, 0.f);
    float R = bn2g[l*H_ + j] * rsqrtf(var + 1e-5f);
    float2 mys = ((const float2*)(ws + OFF_S))[k*H_ + j];
    float a = mys.x * R;
    float c = (mys.y - mean) * R + bn2b[l*H_ + j];
    float lo = (k > 0) ? ws[OFF_TS + k - 1] : -INFINITY;
    float hi = (k < NBINS - 1) ? ws[OFF_TS + k] : INFINITY;
    bool actv = (k == 0) ? ((a < 0.f) || (a == 0.f && c > 0.f))
                         : (fmaf(a, lo, c) > 0.f);
    float u = (a != 0.f) ? (-c / a) : INFINITY;
    bool rel = (a != 0.f) && (u > lo) && (u < hi);
    float key = rel ? u : INFINITY;
    skey[j] = key;
    __syncthreads();
    int rk = 0;
    for (int q = 0; q < H_; q++) {
        float kq = skey[q];
        rk += ((kq < key) || (kq == key && q < j)) ? 1 : 0;
    }
    float w0 = wf[l*2*H_ + j], w1 = wf[l*2*H_ + H_ + j];
    float4 bb = bsum4(actv ? make_float4(w0*a, w0*c, w1*a, w1*c)
                           : make_float4(0.f, 0.f, 0.f, 0.f), red, j);
    float sg = rel ? ((a > 0.f) ? 1.f : -1.f) : 0.f;
    sval[rk] = key;
    sc4[rk] = make_float4(sg*w0*a, sg*w0*c, sg*w1*a, sg*w1*c);
    __syncthreads();
    for (int off = 1; off < H_; off <<= 1) {
        float4 add = (j >= off) ? sc4[j - off] : make_float4(0.f, 0.f, 0.f, 0.f);
        __syncthreads();
        sc4[j].x += add.x; sc4[j].y += add.y; sc4[j].z += add.z; sc4[j].w += add.w;
        __syncthreads();
    }
    float bfx = bf[2*l], bfy = bf[2*l + 1];
    ws[OFF_U + k*H_ + j] = sval[j];
    if (j < 8) ws[OFF_UP + k*8 + j] = sval[16*j + 15];
    float4* Cg = (float4*)(ws + OFF_C) + k * 132;
    float4 sj = sc4[j];
    Cg[j + 1] = make_float4(bb.x + sj.x, bb.y + bfx + sj.y,
                            bb.z + sj.z, bb.w + bfy + sj.w);
    if (j == 0) Cg[0] = make_float4(bb.x, bb.y + bfx, bb.z, bb.w + bfy);
}

// 256x1024: per-sample 2-round search + segment eval + coupling update,
// fused next-layer xin stats. Last layer: sigmoid + logdet output.
__global__ __launch_bounds__(1024) void k_step(
    const float* __restrict__ x,
    float* __restrict__ ws, float* __restrict__ out,
    int l, int rev, int last) {
    __shared__ float4 lup4[NBINS * 2];
    __shared__ float rsc[32];
    const int tid = threadIdx.x;
    float* lup = (float*)lup4;
    for (int e = tid; e < NBINS * 8; e += 1024) lup[e] = ws[OFF_UP + e];
    __syncthreads();
    const int b = blockIdx.x * 1024 + tid;
    float x0v, x1v, sl;
    if (l == 0) {
        float2 xv = ((const float2*)x)[b];
        x0v = xv.x; x1v = xv.y; sl = 0.f;
    } else {
        x0v = ws[OFF_X0 + b]; x1v = ws[OFF_X1 + b]; sl = ws[OFF_SL + b];
    }
    float xin = rev ? x1v : x0v;
    float xo  = rev ? x0v : x1v;
    int kb = ((const unsigned char*)(ws + OFF_KB))[b];
    float4 p0 = lup4[kb*2], p1 = lup4[kb*2 + 1];
    int s16 = (p0.x<xin)+(p0.y<xin)+(p0.z<xin)+(p0.w<xin)
            + (p1.x<xin)+(p1.y<xin)+(p1.z<xin)+(p1.w<xin);
    if (s16 > 7) s16 = 7;
    const float4* Ur = (const float4*)(ws + OFF_U + kb*H_ + s16*16);
    float4 q0 = Ur[0], q1 = Ur[1], q2 = Ur[2], q3 = Ur[3];
    int c2 = (q0.x<xin)+(q0.y<xin)+(q0.z<xin)+(q0.w<xin)
           + (q1.x<xin)+(q1.y<xin)+(q1.z<xin)+(q1.w<xin)
           + (q2.x<xin)+(q2.y<xin)+(q2.z<xin)+(q2.w<xin)
           + (q3.x<xin)+(q3.y<xin)+(q3.z<xin)+(q3.w<xin);
    int s = s16 * 16 + c2;
    float4 C = ((const float4*)(ws + OFF_C))[kb*132 + s];
    float stx = fmaf(C.x, xin, C.y);
    float sty = fmaf(C.z, xin, C.w);
    float sv = tanhf(stx);
    float y = expf(sv) * xo + sty;
    sl += sv;
    if (!last) {
        if (rev) {
            ws[OFF_X0 + b] = y;
            if (l == 0) ws[OFF_X1 + b] = x1v;
        } else {
            ws[OFF_X1 + b] = y;
        }
        ws[OFF_SL + b] = sl;
        float s1 = y, s2 = y * y;
        for (int off = 32; off; off >>= 1) {
            s1 += __shfl_down(s1, off); s2 += __shfl_down(s2, off);
        }
        int lane = tid & 63, wid = tid >> 6;
        if (lane == 0) { rsc[wid] = s1; rsc[16 + wid] = s2; }
        __syncthreads();
        if (tid == 0) {
            float aa = 0.f, cc = 0.f;
            for (int w = 0; w < 16; w++) { aa += rsc[w]; cc += rsc[16 + w]; }
            atomicAdd(&ws[OFF_STAT + 2*(l+1)], aa);
            atomicAdd(&ws[OFF_STAT + 2*(l+1) + 1], cc);
        }
    } else {
        float z0 = 1.f / (1.f + expf(-x0v));
        float z1 = 1.f / (1.f + expf(-y));
        ((float2*)out)[b] = make_float2(z0, z1);
        out[2*BN_ + b] = sl + logf(z0 * (1.f - z0) + 1e-4f)
                            + logf(z1 * (1.f - z1) + 1e-4f);
    }
}

extern "C" void kernel_launch(void* const* d_in, const int* in_sizes, int n_in,
                              void* d_out, int out_size, void* d_ws, size_t ws_size,
                              hipStream_t stream) {
    const float* x    = (const float*)d_in[0];
    const float* v1   = (const float*)d_in[1];
    const float* g1   = (const float*)d_in[2];
    // d_in[3] = b1: cancels exactly inside BN1 (affine input), unused.
    const float* bn1g = (const float*)d_in[4];
    const float* bn1b = (const float*)d_in[5];
    const float* v2   = (const float*)d_in[6];
    const float* g2   = (const float*)d_in[7];
    const float* b2   = (const float*)d_in[8];
    const float* bn2g = (const float*)d_in[9];
    const float* bn2b = (const float*)d_in[10];
    const float* wf   = (const float*)d_in[11];
    const float* bf   = (const float*)d_in[12];
    float* ws  = (float*)d_ws;
    float* out = (float*)d_out;

    hipMemsetAsync(ws, 0, 2064 * sizeof(float), stream);   // stats + pm/pe
    k_init<<<256, 1024, 0, stream>>>(x, v2, g2, ws);
    for (int l = 0; l < 8; l++) {
        int rev = (l % 2 == 0) ? 1 : 0;
        int last = (l == 7) ? 1 : 0;
        k_bin<<<256, 1024, 0, stream>>>(x, v1, g1, bn1g, bn1b, b2, ws, l, rev);
        k_prep2<<<NBINS, 128, 0, stream>>>(bn2g, bn2b, wf, bf, ws, l);
        k_step<<<256, 1024, 0, stream>>>(x, ws, out, l, rev, last);
    }
}